// Round 1
// baseline (705.500 us; speedup 1.0000x reference)
//
#include <hip/hip_runtime.h>

#define T_STEPS 512
#define IN_DIM 11
#define H_DIM 16
#define LOG2E 1.44269504088896340736f

// Broadcast a float from lane l (0..63) to an SGPR-resident uniform value.
__device__ __forceinline__ float bcast_lane(float v, int l) {
    return __builtin_bit_cast(float,
        __builtin_amdgcn_readlane(__builtin_bit_cast(int, v), l));
}

// One wave per batch element. Lane j = gate row j (i:0-15, f:16-31, g:32-47, o:48-63),
// matching PyTorch/reference 4H packing. Both LSTM layers fused; h1 never hits memory.
// Weights live in per-lane VGPRs (loaded once); h-state is broadcast via v_readlane
// so recurrent FMAs are v_fmac v,s,v (100% MAC efficiency, no LDS for weights).
// Activation: sigmoid/tanh unified as A*rcp(1+exp2(M*x))+B with M folded into the
// weights/biases at register-load time.
__global__ __launch_bounds__(256, 4) void lstm2_head(
    const float* __restrict__ x,
    const float* __restrict__ Wih1, const float* __restrict__ Whh1,
    const float* __restrict__ bih1, const float* __restrict__ bhh1,
    const float* __restrict__ Wih2, const float* __restrict__ Whh2,
    const float* __restrict__ bih2, const float* __restrict__ bhh2,
    const float* __restrict__ Wd1, const float* __restrict__ bd1,
    const float* __restrict__ Wd2, const float* __restrict__ bd2,
    const float* __restrict__ Wd3, const float* __restrict__ bd3,
    float* __restrict__ out)
{
    const int lane = threadIdx.x & 63;
    // Force wave-uniformity of the batch index so x loads become s_load.
    const int wid = __builtin_amdgcn_readfirstlane((int)(threadIdx.x >> 6));
    const int b = blockIdx.x * 4 + wid;

    const int gt = lane >> 4;                  // 0:i 1:f 2:g(tanh) 3:o
    const bool is_t = (gt == 2);
    const float M  = is_t ? (-2.0f * LOG2E) : (-LOG2E);
    const float Aa = is_t ? 2.0f : 1.0f;
    const float Bc = is_t ? -1.0f : 0.0f;

    // Per-lane weight rows (scaled by M so activation needs no pre-multiply).
    float wi1[IN_DIM], wh1[H_DIM], wi2[H_DIM], wh2[H_DIM];
    #pragma unroll
    for (int k = 0; k < IN_DIM; ++k) wi1[k] = M * Wih1[lane * IN_DIM + k];
    #pragma unroll
    for (int k = 0; k < H_DIM; ++k)  wh1[k] = M * Whh1[lane * H_DIM + k];
    #pragma unroll
    for (int k = 0; k < H_DIM; ++k)  wi2[k] = M * Wih2[lane * H_DIM + k];
    #pragma unroll
    for (int k = 0; k < H_DIM; ++k)  wh2[k] = M * Whh2[lane * H_DIM + k];
    const float bb1 = M * (bih1[lane] + bhh1[lane]);
    const float bb2 = M * (bih2[lane] + bhh2[lane]);

    const float* __restrict__ xb = x + (size_t)b * (T_STEPS * IN_DIM);

    float c1 = 0.f, c2 = 0.f, h1v = 0.f, h2v = 0.f, ssum = 0.f;
    // Wave-uniform h-state (SGPRs via readlane).
    float h1s[H_DIM], h2s[H_DIM];
    #pragma unroll
    for (int k = 0; k < H_DIM; ++k) { h1s[k] = 0.f; h2s[k] = 0.f; }

    const int sl  = lane & 15;
    const int slf = sl + 16, slg = sl + 32, slo = sl + 48;

    // Prefetch x for t=0 (uniform address -> scalar loads).
    float xs[IN_DIM];
    #pragma unroll
    for (int k = 0; k < IN_DIM; ++k) xs[k] = xb[k];

    for (int t = 0; t < T_STEPS; ++t) {
        // Prefetch next step's x so the s_load latency overlaps the body.
        float xn[IN_DIM];
        const int tn = (t + 1 < T_STEPS) ? (t + 1) : (T_STEPS - 1);
        #pragma unroll
        for (int k = 0; k < IN_DIM; ++k) xn[k] = xb[tn * IN_DIM + k];

        // ---------------- layer 1 gate preact (M-scaled) ----------------
        float ga = bb1, gb = 0.f;
        #pragma unroll
        for (int k = 0; k + 1 < IN_DIM; k += 2) {
            ga = __builtin_fmaf(wi1[k],     xs[k],     ga);
            gb = __builtin_fmaf(wi1[k + 1], xs[k + 1], gb);
        }
        ga = __builtin_fmaf(wi1[IN_DIM - 1], xs[IN_DIM - 1], ga);
        #pragma unroll
        for (int k = 0; k < H_DIM; k += 2) {
            ga = __builtin_fmaf(wh1[k],     h1s[k],     ga);
            gb = __builtin_fmaf(wh1[k + 1], h1s[k + 1], gb);
        }
        const float g1 = ga + gb;
        const float a1 = __builtin_fmaf(
            Aa, __builtin_amdgcn_rcpf(1.0f + __builtin_amdgcn_exp2f(g1)), Bc);

        // Gather f,g,o into home lanes 0..15 (lane k holds c1[k]).
        const float f1 = __shfl(a1, slf, 64);
        const float G1 = __shfl(a1, slg, 64);
        const float o1 = __shfl(a1, slo, 64);
        c1 = __builtin_fmaf(f1, c1, a1 * G1);
        const float tc1 = __builtin_fmaf(2.0f,
            __builtin_amdgcn_rcpf(1.0f + __builtin_amdgcn_exp2f(-2.0f * LOG2E * c1)), -1.0f);
        h1v = o1 * tc1;
        #pragma unroll
        for (int k = 0; k < H_DIM; ++k) h1s[k] = bcast_lane(h1v, k);

        // ---------------- layer 2 ----------------
        float pa = bb2, pb = 0.f;
        #pragma unroll
        for (int k = 0; k < H_DIM; k += 2) {
            pa = __builtin_fmaf(wi2[k],     h1s[k],     pa);
            pb = __builtin_fmaf(wi2[k + 1], h1s[k + 1], pb);
        }
        #pragma unroll
        for (int k = 0; k < H_DIM; k += 2) {
            pa = __builtin_fmaf(wh2[k],     h2s[k],     pa);
            pb = __builtin_fmaf(wh2[k + 1], h2s[k + 1], pb);
        }
        const float g2 = pa + pb;
        const float a2 = __builtin_fmaf(
            Aa, __builtin_amdgcn_rcpf(1.0f + __builtin_amdgcn_exp2f(g2)), Bc);

        const float f2 = __shfl(a2, slf, 64);
        const float G2 = __shfl(a2, slg, 64);
        const float o2 = __shfl(a2, slo, 64);
        c2 = __builtin_fmaf(f2, c2, a2 * G2);
        const float tc2 = __builtin_fmaf(2.0f,
            __builtin_amdgcn_rcpf(1.0f + __builtin_amdgcn_exp2f(-2.0f * LOG2E * c2)), -1.0f);
        h2v = o2 * tc2;
        #pragma unroll
        for (int k = 0; k < H_DIM; ++k) h2s[k] = bcast_lane(h2v, k);

        // Online softmax-over-time denominator (|h2|<1 -> no max needed).
        ssum += __builtin_amdgcn_exp2f(LOG2E * h2v);

        #pragma unroll
        for (int k = 0; k < IN_DIM; ++k) xs[k] = xn[k];
    }

    // s[b,k] = exp(h2[b,T-1,k]) / sum_t exp(h2[b,t,k])   (lanes 0..15 hold k)
    const float sv = __builtin_amdgcn_exp2f(LOG2E * h2v) / ssum;

    float ssb[H_DIM];
    #pragma unroll
    for (int k = 0; k < H_DIM; ++k) ssb[k] = bcast_lane(sv, k);

    // Dense head: 16 -> 8 -> 8 -> 3, then softmax over 3 (one-time cost).
    const int r8 = lane & 7;
    float acc1 = bd1[r8];
    #pragma unroll
    for (int k = 0; k < H_DIM; ++k)
        acc1 = __builtin_fmaf(Wd1[r8 * H_DIM + k], ssb[k], acc1);

    float d1s[8];
    #pragma unroll
    for (int j = 0; j < 8; ++j) d1s[j] = bcast_lane(acc1, j);

    float acc2 = bd2[r8];
    #pragma unroll
    for (int k = 0; k < 8; ++k)
        acc2 = __builtin_fmaf(Wd2[r8 * 8 + k], d1s[k], acc2);

    float d2s[8];
    #pragma unroll
    for (int j = 0; j < 8; ++j) d2s[j] = bcast_lane(acc2, j);

    float lg = 0.f;
    if (lane < 3) {
        lg = bd3[lane];
        #pragma unroll
        for (int k = 0; k < 8; ++k)
            lg = __builtin_fmaf(Wd3[lane * 8 + k], d2s[k], lg);
    }
    const float l0 = bcast_lane(lg, 0);
    const float l1 = bcast_lane(lg, 1);
    const float l2 = bcast_lane(lg, 2);
    const float mx = fmaxf(l0, fmaxf(l1, l2));
    const float e0 = __builtin_amdgcn_exp2f(LOG2E * (l0 - mx));
    const float e1 = __builtin_amdgcn_exp2f(LOG2E * (l1 - mx));
    const float e2 = __builtin_amdgcn_exp2f(LOG2E * (l2 - mx));
    const float inv = 1.0f / (e0 + e1 + e2);
    if (lane < 3) {
        const float ev = (lane == 0) ? e0 : ((lane == 1) ? e1 : e2);
        out[b * 3 + lane] = ev * inv;
    }
}

extern "C" void kernel_launch(void* const* d_in, const int* in_sizes, int n_in,
                              void* d_out, int out_size, void* d_ws, size_t ws_size,
                              hipStream_t stream) {
    (void)in_sizes; (void)n_in; (void)out_size; (void)d_ws; (void)ws_size;
    const float* x    = (const float*)d_in[0];
    const float* Wih1 = (const float*)d_in[1];
    const float* Whh1 = (const float*)d_in[2];
    const float* bih1 = (const float*)d_in[3];
    const float* bhh1 = (const float*)d_in[4];
    const float* Wih2 = (const float*)d_in[5];
    const float* Whh2 = (const float*)d_in[6];
    const float* bih2 = (const float*)d_in[7];
    const float* bhh2 = (const float*)d_in[8];
    const float* Wd1  = (const float*)d_in[9];
    const float* bd1  = (const float*)d_in[10];
    const float* Wd2  = (const float*)d_in[11];
    const float* bd2  = (const float*)d_in[12];
    const float* Wd3  = (const float*)d_in[13];
    const float* bd3  = (const float*)d_in[14];

    // 4096 batch elements, 1 wave each, 4 waves per 256-thread block.
    lstm2_head<<<dim3(4096 / 4), dim3(256), 0, stream>>>(
        x, Wih1, Whh1, bih1, bhh1, Wih2, Whh2, bih2, bhh2,
        Wd1, bd1, Wd2, bd2, Wd3, bd3, (float*)d_out);
}

// Round 2
// 637.532 us; speedup vs baseline: 1.1066x; 1.1066x over previous
//
#include <hip/hip_runtime.h>

#define T_STEPS 512
#define IN_DIM 11
#define H_DIM 16
#define LOG2E 1.44269504088896340736f

// DPP quad_perm broadcast within each group of 4 consecutive lanes.
// CTRL = p0 | p1<<2 | p2<<4 | p3<<6. Full-rate VALU, no LDS pipe.
template<int CTRL>
__device__ __forceinline__ float qperm(float v) {
    return __builtin_bit_cast(float,
        __builtin_amdgcn_update_dpp(0, __builtin_bit_cast(int, v),
                                    CTRL, 0xf, 0xf, true));
}

// Broadcast a float from lane l to a wave-uniform (SGPR) value.
__device__ __forceinline__ float bcast_lane(float v, int l) {
    return __builtin_bit_cast(float,
        __builtin_amdgcn_readlane(__builtin_bit_cast(int, v), l));
}

// One wave per batch element. Lane l = (r = l>>2, gate = l&3) so the four
// gates (i,f,g,o) of hidden index r occupy one DPP quad: the f/g/o gathers
// for the cell update are v_mov_dpp quad_perm (no ds_bpermute, no lgkm wait).
// Weight rows per lane in VGPRs (row = gate*16 + r, matching i,f,g,o packing);
// h-state broadcast via v_readlane from lane 4k. Activation folded:
// sigmoid/tanh = A*rcp(1+exp2(M*z))+B with M pre-multiplied into weights.
__global__ __launch_bounds__(256, 4) void lstm2_head(
    const float* __restrict__ x,
    const float* __restrict__ Wih1, const float* __restrict__ Whh1,
    const float* __restrict__ bih1, const float* __restrict__ bhh1,
    const float* __restrict__ Wih2, const float* __restrict__ Whh2,
    const float* __restrict__ bih2, const float* __restrict__ bhh2,
    const float* __restrict__ Wd1, const float* __restrict__ bd1,
    const float* __restrict__ Wd2, const float* __restrict__ bd2,
    const float* __restrict__ Wd3, const float* __restrict__ bd3,
    float* __restrict__ out)
{
    const int lane = threadIdx.x & 63;
    const int wid = __builtin_amdgcn_readfirstlane((int)(threadIdx.x >> 6));
    const int b = blockIdx.x * 4 + wid;

    const int r  = lane >> 2;        // hidden index 0..15
    const int gt = lane & 3;         // 0:i 1:f 2:g(tanh) 3:o
    const int row = gt * H_DIM + r;  // row in packed 4H weight matrices

    const bool is_t = (gt == 2);
    const float M   = is_t ? (-2.0f * LOG2E) : (-LOG2E);
    const float vAa = is_t ? 2.0f : 1.0f;
    const float vBc = is_t ? -1.0f : 0.0f;

    float wi1[IN_DIM], wh1[H_DIM], wi2[H_DIM], wh2[H_DIM];
    #pragma unroll
    for (int k = 0; k < IN_DIM; ++k) wi1[k] = M * Wih1[row * IN_DIM + k];
    #pragma unroll
    for (int k = 0; k < H_DIM; ++k)  wh1[k] = M * Whh1[row * H_DIM + k];
    #pragma unroll
    for (int k = 0; k < H_DIM; ++k)  wi2[k] = M * Wih2[row * H_DIM + k];
    #pragma unroll
    for (int k = 0; k < H_DIM; ++k)  wh2[k] = M * Whh2[row * H_DIM + k];
    const float bb1 = M * (bih1[row] + bhh1[row]);
    const float bb2 = M * (bih2[row] + bhh2[row]);

    const float* __restrict__ xb = x + (size_t)b * (T_STEPS * IN_DIM);

    float c1 = 0.f, c2 = 0.f, h1v = 0.f, h2v = 0.f, ssum = 0.f;
    float h1s[H_DIM], h2s[H_DIM];
    #pragma unroll
    for (int k = 0; k < H_DIM; ++k) { h1s[k] = 0.f; h2s[k] = 0.f; }

    // Ping-pong x buffers (uniform address -> scalar loads), distance-2 prefetch.
    float xs0[IN_DIM], xs1[IN_DIM];
    #pragma unroll
    for (int k = 0; k < IN_DIM; ++k) xs0[k] = xb[k];
    #pragma unroll
    for (int k = 0; k < IN_DIM; ++k) xs1[k] = xb[IN_DIM + k];

    // gate act -> quad gathers (DPP) -> cell update -> tanh -> h
    #define LAYER(GSUM, C, HV)                                                  \
        {                                                                       \
            const float a_ = __builtin_fmaf(vAa,                                \
                __builtin_amdgcn_rcpf(1.0f + __builtin_amdgcn_exp2f(GSUM)),     \
                vBc);                                                           \
            const float gi_ = qperm<0x00>(a_);                                  \
            const float gf_ = qperm<0x55>(a_);                                  \
            const float gg_ = qperm<0xAA>(a_);                                  \
            const float go_ = qperm<0xFF>(a_);                                  \
            C = __builtin_fmaf(gf_, C, gi_ * gg_);                              \
            const float tc_ = __builtin_fmaf(2.0f,                              \
                __builtin_amdgcn_rcpf(1.0f +                                    \
                    __builtin_amdgcn_exp2f(-2.0f * LOG2E * C)), -1.0f);         \
            HV = go_ * tc_;                                                     \
        }

    #define STEP(XS)                                                            \
        {                                                                       \
            /* L2 recurrent partial first: depends only on h2(t-1), overlaps    \
               everything below (off the h1 critical path). */                  \
            float pa = bb2, pb = 0.f;                                           \
            _Pragma("unroll")                                                   \
            for (int k = 0; k < H_DIM; k += 2) {                                \
                pa = __builtin_fmaf(wh2[k],     h2s[k],     pa);                \
                pb = __builtin_fmaf(wh2[k + 1], h2s[k + 1], pb);                \
            }                                                                   \
            float ga = bb1, gb = 0.f;                                           \
            _Pragma("unroll")                                                   \
            for (int k = 0; k + 1 < IN_DIM; k += 2) {                           \
                ga = __builtin_fmaf(wi1[k],     XS[k],     ga);                 \
                gb = __builtin_fmaf(wi1[k + 1], XS[k + 1], gb);                 \
            }                                                                   \
            ga = __builtin_fmaf(wi1[IN_DIM - 1], XS[IN_DIM - 1], ga);           \
            _Pragma("unroll")                                                   \
            for (int k = 0; k < H_DIM; k += 2) {                                \
                ga = __builtin_fmaf(wh1[k],     h1s[k],     ga);                \
                gb = __builtin_fmaf(wh1[k + 1], h1s[k + 1], gb);                \
            }                                                                   \
            float h1n, h2n;                                                     \
            LAYER(ga + gb, c1, h1n)                                             \
            h1v = h1n;                                                          \
            _Pragma("unroll")                                                   \
            for (int k = 0; k < H_DIM; ++k) h1s[k] = bcast_lane(h1v, 4 * k);    \
            _Pragma("unroll")                                                   \
            for (int k = 0; k < H_DIM; k += 2) {                                \
                pa = __builtin_fmaf(wi2[k],     h1s[k],     pa);                \
                pb = __builtin_fmaf(wi2[k + 1], h1s[k + 1], pb);                \
            }                                                                   \
            LAYER(pa + pb, c2, h2n)                                             \
            h2v = h2n;                                                          \
            _Pragma("unroll")                                                   \
            for (int k = 0; k < H_DIM; ++k) h2s[k] = bcast_lane(h2v, 4 * k);    \
            ssum += __builtin_amdgcn_exp2f(LOG2E * h2v);                        \
        }

    for (int t = 0; t < T_STEPS; t += 2) {
        STEP(xs0)
        {
            const int tn = (t + 2 < T_STEPS) ? (t + 2) : (T_STEPS - 1);
            const float* __restrict__ p = xb + tn * IN_DIM;
            #pragma unroll
            for (int k = 0; k < IN_DIM; ++k) xs0[k] = p[k];
        }
        STEP(xs1)
        {
            const int tn = (t + 3 < T_STEPS) ? (t + 3) : (T_STEPS - 1);
            const float* __restrict__ p = xb + tn * IN_DIM;
            #pragma unroll
            for (int k = 0; k < IN_DIM; ++k) xs1[k] = p[k];
        }
    }
    #undef STEP
    #undef LAYER

    // s[b,k] = exp(h2[b,T-1,k]) / sum_t exp(h2[b,t,k]); h2v replicated per quad.
    const float sv = __builtin_amdgcn_exp2f(LOG2E * h2v) / ssum;

    float ssb[H_DIM];
    #pragma unroll
    for (int k = 0; k < H_DIM; ++k) ssb[k] = bcast_lane(sv, 4 * k);

    // Dense head: 16 -> 8 -> 8 -> 3, then softmax over 3 (one-time cost).
    const int r8 = lane & 7;
    float acc1 = bd1[r8];
    #pragma unroll
    for (int k = 0; k < H_DIM; ++k)
        acc1 = __builtin_fmaf(Wd1[r8 * H_DIM + k], ssb[k], acc1);

    float d1s[8];
    #pragma unroll
    for (int j = 0; j < 8; ++j) d1s[j] = bcast_lane(acc1, j);

    float acc2 = bd2[r8];
    #pragma unroll
    for (int k = 0; k < 8; ++k)
        acc2 = __builtin_fmaf(Wd2[r8 * 8 + k], d1s[k], acc2);

    float d2s[8];
    #pragma unroll
    for (int j = 0; j < 8; ++j) d2s[j] = bcast_lane(acc2, j);

    float lg = 0.f;
    if (lane < 3) {
        lg = bd3[lane];
        #pragma unroll
        for (int k = 0; k < 8; ++k)
            lg = __builtin_fmaf(Wd3[lane * 8 + k], d2s[k], lg);
    }
    const float l0 = bcast_lane(lg, 0);
    const float l1 = bcast_lane(lg, 1);
    const float l2 = bcast_lane(lg, 2);
    const float mx = fmaxf(l0, fmaxf(l1, l2));
    const float e0 = __builtin_amdgcn_exp2f(LOG2E * (l0 - mx));
    const float e1 = __builtin_amdgcn_exp2f(LOG2E * (l1 - mx));
    const float e2 = __builtin_amdgcn_exp2f(LOG2E * (l2 - mx));
    const float inv = 1.0f / (e0 + e1 + e2);
    if (lane < 3) {
        const float ev = (lane == 0) ? e0 : ((lane == 1) ? e1 : e2);
        out[b * 3 + lane] = ev * inv;
    }
}

extern "C" void kernel_launch(void* const* d_in, const int* in_sizes, int n_in,
                              void* d_out, int out_size, void* d_ws, size_t ws_size,
                              hipStream_t stream) {
    (void)in_sizes; (void)n_in; (void)out_size; (void)d_ws; (void)ws_size;
    const float* x    = (const float*)d_in[0];
    const float* Wih1 = (const float*)d_in[1];
    const float* Whh1 = (const float*)d_in[2];
    const float* bih1 = (const float*)d_in[3];
    const float* bhh1 = (const float*)d_in[4];
    const float* Wih2 = (const float*)d_in[5];
    const float* Whh2 = (const float*)d_in[6];
    const float* bih2 = (const float*)d_in[7];
    const float* bhh2 = (const float*)d_in[8];
    const float* Wd1  = (const float*)d_in[9];
    const float* bd1  = (const float*)d_in[10];
    const float* Wd2  = (const float*)d_in[11];
    const float* bd2  = (const float*)d_in[12];
    const float* Wd3  = (const float*)d_in[13];
    const float* bd3  = (const float*)d_in[14];

    lstm2_head<<<dim3(4096 / 4), dim3(256), 0, stream>>>(
        x, Wih1, Whh1, bih1, bhh1, Wih2, Whh2, bih2, bhh2,
        Wd1, bd1, Wd2, bd2, Wd3, bd3, (float*)d_out);
}

// Round 3
// 478.013 us; speedup vs baseline: 1.4759x; 1.3337x over previous
//
#include <hip/hip_runtime.h>

#define T_STEPS 512
#define IN_DIM 11
#define H_DIM 16
#define ROW_F (T_STEPS * IN_DIM)   // 5632 floats per batch row
#define CHUNK_T 16                 // t-steps per x chunk
#define CHUNK_F (CHUNK_T * IN_DIM) // 176 floats per chunk
#define N_CHUNK (T_STEPS / CHUNK_T)
#define LOG2E 1.44269504088896340736f

typedef float v2f __attribute__((ext_vector_type(2)));

// Packed fp32 FMA (v_pk_fma_f32): 2 MACs per instruction, full rate on CDNA3+.
__device__ __forceinline__ v2f pk_fma(v2f a, v2f b, v2f c) {
    v2f d;
    asm("v_pk_fma_f32 %0, %1, %2, %3" : "=v"(d) : "v"(a), "v"(b), "v"(c));
    return d;
}

// DPP quad_perm broadcast within each group of 4 lanes.
template<int CTRL>
__device__ __forceinline__ float qperm(float v) {
    return __builtin_bit_cast(float,
        __builtin_amdgcn_update_dpp(0, __builtin_bit_cast(int, v),
                                    CTRL, 0xf, 0xf, true));
}

__device__ __forceinline__ float bcast_lane(float v, int l) {
    return __builtin_bit_cast(float,
        __builtin_amdgcn_readlane(__builtin_bit_cast(int, v), l));
}

// One wave per batch element; lane = 4*r + gate (i,f,g,o). Weights per-lane in
// VGPRs, pinned with opaque asm so the allocator cannot rematerialize/reload
// them (round-2 showed VGPR_Count=56 < 59 weight values -> bounced operands).
// h-state broadcast goes through a per-wave LDS slab (write 16 floats, read
// back pairs at uniform address = broadcast) - off the VALU pipe entirely.
// x is staged through LDS in 176-float chunks (one chunk = 16 steps),
// double-buffered, prefetched one chunk ahead: no SMEM in the loop, DS-only
// lgkmcnt, HBM latency covered by ~16 steps.
__global__ __launch_bounds__(256, 4) void lstm2_head(
    const float* __restrict__ x,
    const float* __restrict__ Wih1, const float* __restrict__ Whh1,
    const float* __restrict__ bih1, const float* __restrict__ bhh1,
    const float* __restrict__ Wih2, const float* __restrict__ Whh2,
    const float* __restrict__ bih2, const float* __restrict__ bhh2,
    const float* __restrict__ Wd1, const float* __restrict__ bd1,
    const float* __restrict__ Wd2, const float* __restrict__ bd2,
    const float* __restrict__ Wd3, const float* __restrict__ bd3,
    float* __restrict__ out)
{
    __shared__ float xlds[4][2][192];   // [wave][buf][chunk floats (176 used)]
    __shared__ float shh[4][2][16];     // [wave][layer][h]

    const int lane = threadIdx.x & 63;
    const int wid = __builtin_amdgcn_readfirstlane((int)(threadIdx.x >> 6));
    const int b = blockIdx.x * 4 + wid;

    const int r   = lane >> 2;          // hidden index 0..15
    const int gt  = lane & 3;           // 0:i 1:f 2:g(tanh) 3:o
    const int row = gt * H_DIM + r;     // row in packed 4H weights

    const bool is_t = (gt == 2);
    const float M   = is_t ? (-2.0f * LOG2E) : (-LOG2E);
    const float vAa = is_t ? 2.0f : 1.0f;
    const float vBc = is_t ? -1.0f : 0.0f;

    // ---- per-lane weights (M-scaled), pinned in VGPRs ----
    float wi1[IN_DIM];
    v2f wh1p[8], wi2p[8], wh2p[8];
    #pragma unroll
    for (int k = 0; k < IN_DIM; ++k) wi1[k] = M * Wih1[row * IN_DIM + k];
    #pragma unroll
    for (int j = 0; j < 8; ++j) {
        wh1p[j] = (v2f){M * Whh1[row * H_DIM + 2 * j], M * Whh1[row * H_DIM + 2 * j + 1]};
        wi2p[j] = (v2f){M * Wih2[row * H_DIM + 2 * j], M * Wih2[row * H_DIM + 2 * j + 1]};
        wh2p[j] = (v2f){M * Whh2[row * H_DIM + 2 * j], M * Whh2[row * H_DIM + 2 * j + 1]};
    }
    const float bb1 = M * (bih1[row] + bhh1[row]);
    const float bb2 = M * (bih2[row] + bhh2[row]);
    #pragma unroll
    for (int k = 0; k < IN_DIM; ++k) asm volatile("" : "+v"(wi1[k]));
    #pragma unroll
    for (int j = 0; j < 8; ++j) {
        asm volatile("" : "+v"(wh1p[j]));
        asm volatile("" : "+v"(wi2p[j]));
        asm volatile("" : "+v"(wh2p[j]));
    }

    const float* __restrict__ xb = x + (size_t)b * ROW_F;
    float* const xl0 = &xlds[wid][0][0];
    float* const xl1 = &xlds[wid][1][0];
    float* const h1mem = &shh[wid][0][0];
    float* const h2mem = &shh[wid][1][0];

    // init h state in LDS (same-wave ordering, no barrier needed)
    h1mem[r] = 0.0f;
    h2mem[r] = 0.0f;

    // prologue: global-load chunk 0 into registers
    float gl0, gl1, gl2;
    {
        const int base = lane;
        gl0 = xb[base];
        gl1 = xb[base + 64];
        gl2 = xb[min(base + 128, ROW_F - 1)];
    }

    float c1 = 0.f, c2 = 0.f, h2v = 0.f, ssum = 0.f;

    for (int ck = 0; ck < N_CHUNK; ++ck) {
        float* const xbuf = (ck & 1) ? xl1 : xl0;
        // stage chunk ck (loaded at previous boundary) into LDS
        xbuf[lane]       = gl0;
        xbuf[lane + 64]  = gl1;
        xbuf[lane + 128] = gl2;
        // prefetch chunk ck+1 (lands well before next boundary)
        if (ck + 1 < N_CHUNK) {
            const int base = (ck + 1) * CHUNK_F + lane;
            gl0 = xb[base];
            gl1 = xb[base + 64];
            gl2 = xb[min(base + 128, ROW_F - 1)];
        }

        #pragma unroll
        for (int t2 = 0; t2 < CHUNK_T; ++t2) {
            const float* const xr = xbuf + t2 * IN_DIM;

            // ---- read prev h1/h2 pairs from LDS (uniform addr broadcast) ----
            v2f a1p = (v2f){0.f, 0.f};
            v2f a2p = (v2f){0.f, 0.f};
            #pragma unroll
            for (int j = 0; j < 8; ++j) {
                v2f hp; hp.x = h2mem[2 * j]; hp.y = h2mem[2 * j + 1];
                a2p = pk_fma(wh2p[j], hp, a2p);
            }
            float a1s = bb1;
            #pragma unroll
            for (int k = 0; k < IN_DIM; ++k)
                a1s = __builtin_fmaf(wi1[k], xr[k], a1s);
            #pragma unroll
            for (int j = 0; j < 8; ++j) {
                v2f hp; hp.x = h1mem[2 * j]; hp.y = h1mem[2 * j + 1];
                a1p = pk_fma(wh1p[j], hp, a1p);
            }

            // ---- layer 1 activation, cell update ----
            const float g1 = a1s + a1p.x + a1p.y;
            const float a1 = __builtin_fmaf(vAa,
                __builtin_amdgcn_rcpf(1.0f + __builtin_amdgcn_exp2f(g1)), vBc);
            {
                const float gi = qperm<0x00>(a1);
                const float gf = qperm<0x55>(a1);
                const float gg = qperm<0xAA>(a1);
                const float go = qperm<0xFF>(a1);
                c1 = __builtin_fmaf(gf, c1, gi * gg);
                const float tc = __builtin_fmaf(2.0f,
                    __builtin_amdgcn_rcpf(1.0f +
                        __builtin_amdgcn_exp2f(-2.0f * LOG2E * c1)), -1.0f);
                const float h1v = go * tc;       // replicated across the quad
                h1mem[r] = h1v;                  // 4-way same-addr write (benign)
            }

            // ---- fresh h1 pairs -> layer 2 input dot ----
            float a2s = bb2;
            #pragma unroll
            for (int j = 0; j < 8; ++j) {
                v2f hp; hp.x = h1mem[2 * j]; hp.y = h1mem[2 * j + 1];
                a2p = pk_fma(wi2p[j], hp, a2p);
            }

            // ---- layer 2 activation, cell update ----
            const float g2 = a2s + a2p.x + a2p.y;
            const float a2 = __builtin_fmaf(vAa,
                __builtin_amdgcn_rcpf(1.0f + __builtin_amdgcn_exp2f(g2)), vBc);
            {
                const float gi = qperm<0x00>(a2);
                const float gf = qperm<0x55>(a2);
                const float gg = qperm<0xAA>(a2);
                const float go = qperm<0xFF>(a2);
                c2 = __builtin_fmaf(gf, c2, gi * gg);
                const float tc = __builtin_fmaf(2.0f,
                    __builtin_amdgcn_rcpf(1.0f +
                        __builtin_amdgcn_exp2f(-2.0f * LOG2E * c2)), -1.0f);
                h2v = go * tc;                   // replicated across the quad
                h2mem[r] = h2v;
            }

            // online softmax-over-time denominator
            ssum += __builtin_amdgcn_exp2f(LOG2E * h2v);
        }
    }

    // s[b,k] = exp(h2[T-1,k]) / sum_t exp(h2[t,k]); h2v replicated per quad.
    const float sv = __builtin_amdgcn_exp2f(LOG2E * h2v) / ssum;

    float ssb[H_DIM];
    #pragma unroll
    for (int k = 0; k < H_DIM; ++k) ssb[k] = bcast_lane(sv, 4 * k);

    // Dense head 16 -> 8 -> 8 -> 3 + softmax (one-time epilogue).
    const int r8 = lane & 7;
    float acc1 = bd1[r8];
    #pragma unroll
    for (int k = 0; k < H_DIM; ++k)
        acc1 = __builtin_fmaf(Wd1[r8 * H_DIM + k], ssb[k], acc1);

    float d1s[8];
    #pragma unroll
    for (int j = 0; j < 8; ++j) d1s[j] = bcast_lane(acc1, j);

    float acc2 = bd2[r8];
    #pragma unroll
    for (int k = 0; k < 8; ++k)
        acc2 = __builtin_fmaf(Wd2[r8 * 8 + k], d1s[k], acc2);

    float d2s[8];
    #pragma unroll
    for (int j = 0; j < 8; ++j) d2s[j] = bcast_lane(acc2, j);

    float lg = 0.f;
    if (lane < 3) {
        lg = bd3[lane];
        #pragma unroll
        for (int k = 0; k < 8; ++k)
            lg = __builtin_fmaf(Wd3[lane * 8 + k], d2s[k], lg);
    }
    const float l0 = bcast_lane(lg, 0);
    const float l1 = bcast_lane(lg, 1);
    const float l2 = bcast_lane(lg, 2);
    const float mx = fmaxf(l0, fmaxf(l1, l2));
    const float e0 = __builtin_amdgcn_exp2f(LOG2E * (l0 - mx));
    const float e1 = __builtin_amdgcn_exp2f(LOG2E * (l1 - mx));
    const float e2 = __builtin_amdgcn_exp2f(LOG2E * (l2 - mx));
    const float inv = 1.0f / (e0 + e1 + e2);
    if (lane < 3) {
        const float ev = (lane == 0) ? e0 : ((lane == 1) ? e1 : e2);
        out[b * 3 + lane] = ev * inv;
    }
}

extern "C" void kernel_launch(void* const* d_in, const int* in_sizes, int n_in,
                              void* d_out, int out_size, void* d_ws, size_t ws_size,
                              hipStream_t stream) {
    (void)in_sizes; (void)n_in; (void)out_size; (void)d_ws; (void)ws_size;
    const float* x    = (const float*)d_in[0];
    const float* Wih1 = (const float*)d_in[1];
    const float* Whh1 = (const float*)d_in[2];
    const float* bih1 = (const float*)d_in[3];
    const float* bhh1 = (const float*)d_in[4];
    const float* Wih2 = (const float*)d_in[5];
    const float* Whh2 = (const float*)d_in[6];
    const float* bih2 = (const float*)d_in[7];
    const float* bhh2 = (const float*)d_in[8];
    const float* Wd1  = (const float*)d_in[9];
    const float* bd1  = (const float*)d_in[10];
    const float* Wd2  = (const float*)d_in[11];
    const float* bd2  = (const float*)d_in[12];
    const float* Wd3  = (const float*)d_in[13];
    const float* bd3  = (const float*)d_in[14];

    lstm2_head<<<dim3(4096 / 4), dim3(256), 0, stream>>>(
        x, Wih1, Whh1, bih1, bhh1, Wih2, Whh2, bih2, bhh2,
        Wd1, bd1, Wd2, bd2, Wd3, bd3, (float*)d_out);
}

// Round 4
// 455.200 us; speedup vs baseline: 1.5499x; 1.0501x over previous
//
#include <hip/hip_runtime.h>

#define T_STEPS 512
#define IN_DIM 11
#define ROW_PAD 12                  // x row padded to 12 floats in LDS
#define H_DIM 16
#define ROW_F (T_STEPS * IN_DIM)    // 5632 floats per batch row
#define CHUNK_T 16                  // t-steps per x chunk
#define CHUNK_F (CHUNK_T * IN_DIM)  // 176 source floats per chunk
#define N_CHUNK (T_STEPS / CHUNK_T)
#define LOG2E 1.44269504088896340736f

typedef float v2f __attribute__((ext_vector_type(2)));

// Packed fp32 FMA (v_pk_fma_f32): 2 MACs/instr, full rate.
__device__ __forceinline__ v2f pk_fma(v2f a, v2f b, v2f c) {
    v2f d;
    asm("v_pk_fma_f32 %0, %1, %2, %3" : "=v"(d) : "v"(a), "v"(b), "v"(c));
    return d;
}

// DPP quad_perm broadcast within each group of 4 lanes.
template<int CTRL>
__device__ __forceinline__ float qperm(float v) {
    return __builtin_bit_cast(float,
        __builtin_amdgcn_update_dpp(0, __builtin_bit_cast(int, v),
                                    CTRL, 0xf, 0xf, true));
}

__device__ __forceinline__ float bcast_lane(float v, int l) {
    return __builtin_bit_cast(float,
        __builtin_amdgcn_readlane(__builtin_bit_cast(int, v), l));
}

// One wave per batch element; lane = 4*r + gate (i,f,g,o quads).
// Weights per-lane in pinned VGPRs (M-scaled so activations need no pre-mul).
// h broadcast via per-wave LDS slab, read back as native ds_read_b64 pairs;
// each pair set is read ONCE per step and stays in registers for the next
// step's recurrent dot (h1r serves wi2*h1(t) now and wh1*h1(t) at t+1).
// x staged through LDS in chunks of 16 steps, rows padded to 12 floats
// (16B-aligned rows -> ds_read_b128; pad weight = 0, pad slot zeroed once).
__global__ __launch_bounds__(256, 4) void lstm2_head(
    const float* __restrict__ x,
    const float* __restrict__ Wih1, const float* __restrict__ Whh1,
    const float* __restrict__ bih1, const float* __restrict__ bhh1,
    const float* __restrict__ Wih2, const float* __restrict__ Whh2,
    const float* __restrict__ bih2, const float* __restrict__ bhh2,
    const float* __restrict__ Wd1, const float* __restrict__ bd1,
    const float* __restrict__ Wd2, const float* __restrict__ bd2,
    const float* __restrict__ Wd3, const float* __restrict__ bd3,
    float* __restrict__ out)
{
    __shared__ float xlds[4][2][212];   // [wave][buf][padded chunk 192 + spill 20]
    __shared__ v2f   shh[4][2][8];      // [wave][layer][h pairs]

    const int lane = threadIdx.x & 63;
    const int wid = __builtin_amdgcn_readfirstlane((int)(threadIdx.x >> 6));
    const int b = blockIdx.x * 4 + wid;

    const int r   = lane >> 2;          // hidden index 0..15
    const int gt  = lane & 3;           // 0:i 1:f 2:g(tanh) 3:o
    const int row = gt * H_DIM + r;     // row in packed 4H weights

    const bool is_t = (gt == 2);
    const float M   = is_t ? (-2.0f * LOG2E) : (-LOG2E);
    const float vAa = is_t ? 2.0f : 1.0f;
    const float vBc = is_t ? -1.0f : 0.0f;

    // ---- per-lane weights (M-scaled), packed in v2f, pinned ----
    v2f wi1p[6], wh1p[8], wi2p[8], wh2p[8];
    #pragma unroll
    for (int j = 0; j < 5; ++j)
        wi1p[j] = (v2f){M * Wih1[row * IN_DIM + 2 * j], M * Wih1[row * IN_DIM + 2 * j + 1]};
    wi1p[5] = (v2f){M * Wih1[row * IN_DIM + 10], 0.0f};   // pad weight = 0
    #pragma unroll
    for (int j = 0; j < 8; ++j) {
        wh1p[j] = (v2f){M * Whh1[row * H_DIM + 2 * j], M * Whh1[row * H_DIM + 2 * j + 1]};
        wi2p[j] = (v2f){M * Wih2[row * H_DIM + 2 * j], M * Wih2[row * H_DIM + 2 * j + 1]};
        wh2p[j] = (v2f){M * Whh2[row * H_DIM + 2 * j], M * Whh2[row * H_DIM + 2 * j + 1]};
    }
    const float bb1 = M * (bih1[row] + bhh1[row]);
    const float bb2 = M * (bih2[row] + bhh2[row]);
    #pragma unroll
    for (int j = 0; j < 6; ++j) asm volatile("" : "+v"(wi1p[j]));
    #pragma unroll
    for (int j = 0; j < 8; ++j) {
        asm volatile("" : "+v"(wh1p[j]));
        asm volatile("" : "+v"(wi2p[j]));
        asm volatile("" : "+v"(wh2p[j]));
    }

    const float* __restrict__ xb = x + (size_t)b * ROW_F;
    float* const xl0 = &xlds[wid][0][0];
    float* const xl1 = &xlds[wid][1][0];
    v2f* const h1mem = &shh[wid][0][0];
    v2f* const h2mem = &shh[wid][1][0];

    // init h state + zero x pad slots (same-wave ordering, no barrier needed)
    if (lane < 16) { h1mem[lane >> 1] = (v2f){0.f, 0.f}; }  // lanes 0..15 cover both
    ((float*)h1mem)[r & 15] = 0.0f;
    ((float*)h2mem)[r & 15] = 0.0f;
    if (lane < 32) {
        const int buf = lane >> 4, rr = lane & 15;
        xlds[wid][buf][rr * ROW_PAD + IN_DIM] = 0.0f;       // pad slot
    }

    // staging offsets: source float f -> padded slot (f/11)*12 + f%11
    const int f1i = lane, f2i = lane + 64, f3i = lane + 128;
    const int p1 = (f1i / IN_DIM) * ROW_PAD + (f1i % IN_DIM);
    const int p2 = (f2i / IN_DIM) * ROW_PAD + (f2i % IN_DIM);
    const int p3 = (f3i / IN_DIM) * ROW_PAD + (f3i % IN_DIM);

    // prologue: global-load chunk 0
    float gl0 = xb[f1i];
    float gl1 = xb[f2i];
    float gl2 = xb[min(f3i, ROW_F - 1)];

    float c1 = 0.f, c2 = 0.f, h2v = 0.f, ssum = 0.f;
    // register-resident h pairs (carried across steps)
    v2f h1r[8], h2r[8];
    #pragma unroll
    for (int j = 0; j < 8; ++j) { h1r[j] = (v2f){0.f, 0.f}; h2r[j] = (v2f){0.f, 0.f}; }

    for (int ck = 0; ck < N_CHUNK; ++ck) {
        float* const xbuf = (ck & 1) ? xl1 : xl0;
        xbuf[p1] = gl0;
        xbuf[p2] = gl1;
        xbuf[p3] = gl2;
        if (ck + 1 < N_CHUNK) {
            const int base = (ck + 1) * CHUNK_F;
            gl0 = xb[base + f1i];
            gl1 = xb[base + f2i];
            gl2 = xb[min(base + f3i, ROW_F - 1)];
        }

        #pragma unroll
        for (int t2 = 0; t2 < CHUNK_T; ++t2) {
            const v2f* const xr = (const v2f*)(xbuf + t2 * ROW_PAD);

            // ---- layer-2 recurrent dot (h2r from prev step, reg-resident) ----
            v2f a2p = pk_fma(wh2p[0], h2r[0], (v2f){bb2, 0.f});
            #pragma unroll
            for (int j = 1; j < 8; ++j) a2p = pk_fma(wh2p[j], h2r[j], a2p);

            // ---- layer-1 preact: x-dot (LDS pairs) + recurrent (h1r regs) ----
            v2f a1p = pk_fma(wi1p[0], xr[0], (v2f){bb1, 0.f});
            #pragma unroll
            for (int j = 1; j < 6; ++j) a1p = pk_fma(wi1p[j], xr[j], a1p);
            #pragma unroll
            for (int j = 0; j < 8; ++j) a1p = pk_fma(wh1p[j], h1r[j], a1p);

            // ---- layer 1 activation + cell ----
            const float g1 = a1p.x + a1p.y;
            const float a1 = __builtin_fmaf(vAa,
                __builtin_amdgcn_rcpf(1.0f + __builtin_amdgcn_exp2f(g1)), vBc);
            {
                const float gi = qperm<0x00>(a1);
                const float gf = qperm<0x55>(a1);
                const float gg = qperm<0xAA>(a1);
                const float go = qperm<0xFF>(a1);
                c1 = __builtin_fmaf(gf, c1, gi * gg);
                const float tc = __builtin_fmaf(2.0f,
                    __builtin_amdgcn_rcpf(1.0f +
                        __builtin_amdgcn_exp2f(-2.0f * LOG2E * c1)), -1.0f);
                ((float*)h1mem)[r] = go * tc;       // quad-replicated write
            }
            // read fresh h1 pairs ONCE: used for wi2 now, wh1 next step
            #pragma unroll
            for (int j = 0; j < 8; ++j) h1r[j] = h1mem[j];

            #pragma unroll
            for (int j = 0; j < 8; ++j) a2p = pk_fma(wi2p[j], h1r[j], a2p);

            // ---- layer 2 activation + cell ----
            const float g2 = a2p.x + a2p.y;
            const float a2 = __builtin_fmaf(vAa,
                __builtin_amdgcn_rcpf(1.0f + __builtin_amdgcn_exp2f(g2)), vBc);
            {
                const float gi = qperm<0x00>(a2);
                const float gf = qperm<0x55>(a2);
                const float gg = qperm<0xAA>(a2);
                const float go = qperm<0xFF>(a2);
                c2 = __builtin_fmaf(gf, c2, gi * gg);
                const float tc = __builtin_fmaf(2.0f,
                    __builtin_amdgcn_rcpf(1.0f +
                        __builtin_amdgcn_exp2f(-2.0f * LOG2E * c2)), -1.0f);
                h2v = go * tc;                      // quad-replicated
                ((float*)h2mem)[r] = h2v;
            }
            // read fresh h2 pairs ONCE for next step's wh2 dot
            #pragma unroll
            for (int j = 0; j < 8; ++j) h2r[j] = h2mem[j];

            ssum += __builtin_amdgcn_exp2f(LOG2E * h2v);
        }
    }

    // s[b,k] = exp(h2[T-1,k]) / sum_t exp(h2[t,k]); h2v replicated per quad.
    const float sv = __builtin_amdgcn_exp2f(LOG2E * h2v) / ssum;

    float ssb[H_DIM];
    #pragma unroll
    for (int k = 0; k < H_DIM; ++k) ssb[k] = bcast_lane(sv, 4 * k);

    // Dense head 16 -> 8 -> 8 -> 3 + softmax (one-time epilogue).
    const int r8 = lane & 7;
    float acc1 = bd1[r8];
    #pragma unroll
    for (int k = 0; k < H_DIM; ++k)
        acc1 = __builtin_fmaf(Wd1[r8 * H_DIM + k], ssb[k], acc1);

    float d1s[8];
    #pragma unroll
    for (int j = 0; j < 8; ++j) d1s[j] = bcast_lane(acc1, j);

    float acc2 = bd2[r8];
    #pragma unroll
    for (int k = 0; k < 8; ++k)
        acc2 = __builtin_fmaf(Wd2[r8 * 8 + k], d1s[k], acc2);

    float d2s[8];
    #pragma unroll
    for (int j = 0; j < 8; ++j) d2s[j] = bcast_lane(acc2, j);

    float lg = 0.f;
    if (lane < 3) {
        lg = bd3[lane];
        #pragma unroll
        for (int k = 0; k < 8; ++k)
            lg = __builtin_fmaf(Wd3[lane * 8 + k], d2s[k], lg);
    }
    const float l0 = bcast_lane(lg, 0);
    const float l1 = bcast_lane(lg, 1);
    const float l2 = bcast_lane(lg, 2);
    const float mx = fmaxf(l0, fmaxf(l1, l2));
    const float e0 = __builtin_amdgcn_exp2f(LOG2E * (l0 - mx));
    const float e1 = __builtin_amdgcn_exp2f(LOG2E * (l1 - mx));
    const float e2 = __builtin_amdgcn_exp2f(LOG2E * (l2 - mx));
    const float inv = 1.0f / (e0 + e1 + e2);
    if (lane < 3) {
        const float ev = (lane == 0) ? e0 : ((lane == 1) ? e1 : e2);
        out[b * 3 + lane] = ev * inv;
    }
}

extern "C" void kernel_launch(void* const* d_in, const int* in_sizes, int n_in,
                              void* d_out, int out_size, void* d_ws, size_t ws_size,
                              hipStream_t stream) {
    (void)in_sizes; (void)n_in; (void)out_size; (void)d_ws; (void)ws_size;
    const float* x    = (const float*)d_in[0];
    const float* Wih1 = (const float*)d_in[1];
    const float* Whh1 = (const float*)d_in[2];
    const float* bih1 = (const float*)d_in[3];
    const float* bhh1 = (const float*)d_in[4];
    const float* Wih2 = (const float*)d_in[5];
    const float* Whh2 = (const float*)d_in[6];
    const float* bih2 = (const float*)d_in[7];
    const float* bhh2 = (const float*)d_in[8];
    const float* Wd1  = (const float*)d_in[9];
    const float* bd1  = (const float*)d_in[10];
    const float* Wd2  = (const float*)d_in[11];
    const float* bd2  = (const float*)d_in[12];
    const float* Wd3  = (const float*)d_in[13];
    const float* bd3  = (const float*)d_in[14];

    lstm2_head<<<dim3(4096 / 4), dim3(256), 0, stream>>>(
        x, Wih1, Whh1, bih1, bhh1, Wih2, Whh2, bih2, bhh2,
        Wd1, bd1, Wd2, bd2, Wd3, bd3, (float*)d_out);
}